// Round 3
// baseline (1005.374 us; speedup 1.0000x reference)
//
#include <hip/hip_runtime.h>
#include <hip/hip_bf16.h>

// Problem constants (fixed by the reference).
constexpr int B = 16;
constexpr int D = 256;       // feature dim
constexpr int L = 4096;      // sequence length
constexpr int N = 4096;      // queries per batch
constexpr int TS = 64;       // l-tile size
constexpr int NT = L / TS;   // 64 tiles per row
constexpr int NCHAIN = B * (D / 64);   // 64 lookback chains

typedef float v4f __attribute__((ext_vector_type(4)));

// ---------------------------------------------------------------------------
// K0: zero the lookback flags (ws is re-poisoned to 0xAA before every call).
// ---------------------------------------------------------------------------
__global__ __launch_bounds__(256) void init_flags(int* __restrict__ flags) {
    int i = blockIdx.x * 256 + threadIdx.x;
    if (i < NCHAIN * NT) flags[i] = 0;
}

// ---------------------------------------------------------------------------
// K1: single-pass fused scan + transpose with decoupled lookback.
// Block = (chain = b*4 + dt, t). blockIdx = chain*NT + t, so within a chain
// predecessors have lower blockIdx (HW dispatches in order -> no deadlock:
// the lowest unfinished block never waits on an unfinished predecessor).
//  phase 1: float4 global loads -> LDS tile[64][65] (2-way banks, free)
//  phase 2: 4 waves shuffle-scan 16 rows each; row totals -> aggs[]
//  wave 0 : publish aggregate (release, agent scope), lookback over
//           predecessors (acquire), publish inclusive prefix; poff = excl.
//  phase 3: coalesced transpose-store of (local scan + poff) along d.
// cs_t[b, l, d] = sum feat[b, d, 0..l);  last tile also writes column L.
// ---------------------------------------------------------------------------
__global__ __launch_bounds__(256) void scan_transpose(
        const float* __restrict__ feat,
        float* __restrict__ cs_t,
        float* __restrict__ aggP,
        float* __restrict__ prefP,
        int* __restrict__ flags) {
    __shared__ float tile[64][65];
    __shared__ float aggs[64];
    __shared__ float poff[64];

    const int bid   = blockIdx.x;
    const int t     = bid & (NT - 1);
    const int chain = bid >> 6;
    const int dt    = chain & 3;
    const int b     = chain >> 2;
    const int d0    = dt * 64;
    const int l0    = t * TS;
    const int tid   = threadIdx.x;

    // phase 1: 64 rows x 16 float4, coalesced (16 consecutive lanes = 256B)
    {
        int j     = tid & 15;        // float4 index within row
        int dbase = tid >> 4;        // 0..15
        #pragma unroll
        for (int r = 0; r < 4; ++r) {
            int dd = dbase + r * 16;
            const float* p = feat + (size_t)(b * D + d0 + dd) * L + l0 + 4 * j;
            float4 v = *(const float4*)p;
            tile[dd][4 * j + 0] = v.x;
            tile[dd][4 * j + 1] = v.y;
            tile[dd][4 * j + 2] = v.z;
            tile[dd][4 * j + 3] = v.w;
        }
    }
    __syncthreads();

    // phase 2: local exclusive scans; lane 63's inclusive value = row total
    {
        int ll = tid & 63, w = tid >> 6;
        #pragma unroll
        for (int r = 0; r < 16; ++r) {
            int dd = w * 16 + r;
            float v = tile[dd][ll];
            float incl = v;
            #pragma unroll
            for (int off = 1; off < 64; off <<= 1) {
                float u = __shfl_up(incl, off, 64);
                if (ll >= off) incl += u;
            }
            tile[dd][ll] = incl - v;
            if (ll == 63) aggs[dd] = incl;
        }
    }
    __syncthreads();

    // wave 0: decoupled lookback (lane = d within the 64-d tile)
    if (tid < 64) {
        const int d = tid;
        const float agg = aggs[d];
        const size_t sidx = (size_t)chain * NT + t;

        if (t > 0) {                              // publish aggregate
            aggP[sidx * 64 + d] = agg;
            __threadfence();
            if (d == 0)
                __hip_atomic_store(&flags[sidx], 1, __ATOMIC_RELEASE,
                                   __HIP_MEMORY_SCOPE_AGENT);
        }

        float run = 0.f;
        for (int tt = t - 1; tt >= 0; --tt) {
            const size_t pidx = (size_t)chain * NT + tt;
            int f, guard = 0;
            do {
                f = __hip_atomic_load(&flags[pidx], __ATOMIC_ACQUIRE,
                                      __HIP_MEMORY_SCOPE_AGENT);
            } while (f == 0 && ++guard < (1 << 22));   // no-hang guard
            if (f == 2) { run += prefP[pidx * 64 + d]; break; }
            run += aggP[pidx * 64 + d];
        }

        if (t < NT - 1) {                         // publish inclusive prefix
            prefP[sidx * 64 + d] = run + agg;
            __threadfence();
            if (d == 0)
                __hip_atomic_store(&flags[sidx], 2, __ATOMIC_RELEASE,
                                   __HIP_MEMORY_SCOPE_AGENT);
        } else {                                  // row total -> column l = L
            cs_t[((size_t)b * (L + 1) + L) * D + d0 + d] = run + agg;
        }
        poff[d] = run;
    }
    __syncthreads();

    // phase 3: coalesced store along d (LDS read (ll+l)%32 -> 2-way, free)
    {
        int ll = tid & 63, w = tid >> 6;
        #pragma unroll
        for (int k = 0; k < 16; ++k) {
            int l = w + k * 4;
            cs_t[((size_t)b * (L + 1) + l0 + l) * D + d0 + ll] =
                tile[ll][l] + poff[ll];
        }
    }
}

// ---------------------------------------------------------------------------
// K2: one wave per query. Rows s/s+1 and e-1/e are contiguous -> 2x 2KB reads.
// Output (201 MB, write-once) via nontemporal stores.
// ---------------------------------------------------------------------------
__global__ __launch_bounds__(256) void pool_queries(const float* __restrict__ cs_t,
                                                    const int* __restrict__ tois,
                                                    float* __restrict__ out) {
    int gw   = (blockIdx.x * blockDim.x + threadIdx.x) >> 6;   // query id
    int lane = threadIdx.x & 63;
    int b = gw >> 12;                 // N == 4096
    int2 se = ((const int2*)tois)[gw];
    int s = se.x, e = se.y;

    const size_t base = (size_t)b * (L + 1);
    const v4f* r_s = (const v4f*)(cs_t + (base + s) * D);
    const v4f* r_e = (const v4f*)(cs_t + (base + e) * D);

    v4f cs0 = r_s[lane];              // row s
    v4f cs1 = r_s[lane + 64];         // row s+1
    v4f ce1 = r_e[lane - 64];         // row e-1
    v4f ce0 = r_e[lane];              // row e

    float inv = 1.0f / (float)(e - s);
    v4f head = cs1 - cs0;
    v4f avg  = (ce0 - cs0) * inv;
    v4f tail = ce0 - ce1;

    v4f* orow = (v4f*)(out + (size_t)gw * (3 * D));
    __builtin_nontemporal_store(head, orow + lane);
    __builtin_nontemporal_store(avg,  orow + 64 + lane);
    __builtin_nontemporal_store(tail, orow + 128 + lane);

    if (gw == 0 && lane < B)
        out[(size_t)B * N * (3 * D) + lane] = (float)((lane + 1) * N);
}

// ---------------------------------------------------------------------------
// Fallback (ws too small): direct span summation.
// ---------------------------------------------------------------------------
__global__ __launch_bounds__(256) void pool_direct(const float* __restrict__ feat,
                                                   const int* __restrict__ tois,
                                                   float* __restrict__ out) {
    int gw   = (blockIdx.x * blockDim.x + threadIdx.x) >> 6;
    int lane = threadIdx.x & 63;
    if (gw >= B * N) return;
    int b = gw >> 12;
    int s = tois[gw * 2 + 0];
    int e = tois[gw * 2 + 1];
    float inv = 1.0f / (float)(e - s);
    float* orow = out + (size_t)gw * (3 * D);
    #pragma unroll
    for (int c = 0; c < 4; ++c) {
        int d = c * 64 + lane;
        const float* f = feat + ((size_t)(b * D + d)) * L;
        float sum = 0.f;
        for (int j = s; j < e; ++j) sum += f[j];
        orow[d]         = f[s];
        orow[D + d]     = sum * inv;
        orow[2 * D + d] = f[e - 1];
    }
    if (gw == 0 && lane < B)
        out[(size_t)B * N * (3 * D) + lane] = (float)((lane + 1) * N);
}

extern "C" void kernel_launch(void* const* d_in, const int* in_sizes, int n_in,
                              void* d_out, int out_size, void* d_ws, size_t ws_size,
                              hipStream_t stream) {
    const float* feat = (const float*)d_in[0];
    const int*   tois = (const int*)d_in[1];
    float*       out  = (float*)d_out;

    const size_t cs_elems   = (size_t)B * (L + 1) * D;        // 16,781,312
    const size_t agg_elems  = (size_t)NCHAIN * NT * 64;       // 262,144
    const size_t flag_elems = (size_t)NCHAIN * NT;            // 4,096
    const size_t need = (cs_elems + 2 * agg_elems + flag_elems) * sizeof(float);

    if (ws_size >= need) {
        float* cs_t  = (float*)d_ws;
        float* aggP  = cs_t + cs_elems;
        float* prefP = aggP + agg_elems;
        int*   flags = (int*)(prefP + agg_elems);

        init_flags<<<(NCHAIN * NT + 255) / 256, 256, 0, stream>>>(flags);
        scan_transpose<<<NCHAIN * NT, 256, 0, stream>>>(feat, cs_t, aggP, prefP, flags);
        pool_queries<<<B * N / 4, 256, 0, stream>>>(cs_t, tois, out);
    } else {
        pool_direct<<<B * N / 4, 256, 0, stream>>>(feat, tois, out);
    }
}